// Round 10
// baseline (274.584 us; speedup 1.0000x reference)
//
#include <hip/hip_runtime.h>
#include <cstdint>
#include <cstddef>

typedef __attribute__((ext_vector_type(8))) short short8;
typedef __attribute__((ext_vector_type(4))) float f32x4;

__device__ __forceinline__ unsigned short bf16_rne(float f) {
  unsigned int u = __float_as_uint(f);
  u += 0x7FFFu + ((u >> 16) & 1u);
  return (unsigned short)(u >> 16);
}

__device__ __forceinline__ short8 pack8(const float* v) {
  short8 r;
#pragma unroll
  for (int e = 0; e < 8; ++e) r[e] = (short)bf16_rne(v[e]);
  return r;
}

// ---------------- fused prep: pack everything fragment-major -----------------
// Packed operand layout: [blk128][kt][ks][grp][row128][e8]
//   elem (blkRow row, k) with k = kt*64 + ks*32 + grp*8 + e
// block ranges:
//   [0,2048)       x pack      (4096 rows)
//   [2048,8048)    mem pack    (12000 rows)
//   [8048,8064)    mem pad rows 12000..12031 -> 0
//   [8064,8576)    Wq pack   (BT 1024x1024, 8 nblk)
//   [8576,9600)    Wkv pack  (BT 2048x1024, 16 nblk)
//   [9600,10112)   Wout pack (BT 1024x1024, 8 nblk)
//   [10112,11264)  zero T2-pad entries of packed K/V
__global__ void __launch_bounds__(256) k_prep(const float* __restrict__ x,
                                              const float* __restrict__ mem,
                                              const float* __restrict__ Wq,
                                              const float* __restrict__ Wkv,
                                              const float* __restrict__ Wout,
                                              unsigned short* __restrict__ xp,
                                              unsigned short* __restrict__ mp,
                                              unsigned short* __restrict__ wqp,
                                              unsigned short* __restrict__ wkvp,
                                              unsigned short* __restrict__ wop,
                                              unsigned short* __restrict__ pk,
                                              unsigned short* __restrict__ pv) {
  const int bid = blockIdx.x, tid = threadIdx.x;
  if (bid < 8048) {
    const float* in; unsigned short* out; int s;
    if (bid < 2048) { in = x;   out = xp; s = bid * 256 + tid; }
    else            { in = mem; out = mp; s = (bid - 2048) * 256 + tid; }
    int row = s >> 7, col8 = s & 127;
    int grp = col8 & 3, ks = (col8 >> 2) & 1, kt = col8 >> 3;
    float4 a = *reinterpret_cast<const float4*>(in + (size_t)row * 1024 + col8 * 8);
    float4 b = *reinterpret_cast<const float4*>(in + (size_t)row * 1024 + col8 * 8 + 4);
    float v[8] = {a.x, a.y, a.z, a.w, b.x, b.y, b.z, b.w};
    int mblk = row >> 7, rloc = row & 127;
    size_t d = ((((size_t)(mblk * 16 + kt) * 2 + ks) * 4 + grp) * 128 + rloc) * 8;
    *reinterpret_cast<short8*>(out + d) = pack8(v);
  } else if (bid < 8064) {
    int p = (bid - 8048) * 256 + tid;          // 32 rows x 128 col8 = 4096
    if (p >= 4096) return;
    int rloc = 96 + (p >> 7), col8 = p & 127;
    int grp = col8 & 3, ks = (col8 >> 2) & 1, kt = col8 >> 3;
    size_t d = ((((size_t)(93 * 16 + kt) * 2 + ks) * 4 + grp) * 128 + rloc) * 8;
    short8 z = {};
    *reinterpret_cast<short8*>(mp + d) = z;
  } else if (bid < 10112) {
    const float* W; unsigned short* out; int C, w0;
    if (bid < 8576)      { W = Wq;   out = wqp;  C = 1024; w0 = (bid - 8064) * 256 + tid; }
    else if (bid < 9600) { W = Wkv;  out = wkvp; C = 2048; w0 = (bid - 8576) * 256 + tid; }
    else                 { W = Wout; out = wop;  C = 1024; w0 = (bid - 9600) * 256 + tid; }
    int rowN = w0 & 127; int t = w0 >> 7;
    int grp = t & 3; t >>= 2;
    int ks = t & 1; t >>= 1;
    int kt = t & 15; int nblk = t >> 4;
    int n = nblk * 128 + rowN;
    int k0 = kt * 64 + ks * 32 + grp * 8;
    float v[8];
#pragma unroll
    for (int e = 0; e < 8; ++e) v[e] = W[(size_t)(k0 + e) * C + n];
    *reinterpret_cast<short8*>(out + (size_t)w0 * 8) = pack8(v);
  } else {
    int i = (bid - 10112) * 256 + tid;   // 128*36*64 = 294912
    if (i >= 128 * 36 * 64) return;
    int head = i / (36 * 64);
    int rem = i - head * (36 * 64);
    int t2 = rem / 64 + 1500;
    int dk = rem & 63;
    size_t ik = ((size_t)(head * 24 + 23) * 8 + (dk >> 3)) * 512 + (t2 & 63) * 8 + (dk & 7);
    size_t iv = ((size_t)(head * 24 + 23) * 8 + ((t2 >> 3) & 7)) * 512 + dk * 8 + (t2 & 7);
    pk[ik] = 0;
    pv[iv] = 0;
  }
}

// ---------------- barrier-free packed-fragment MFMA GEMM, 128x128, BK=64 -----
// No LDS, no __syncthreads. Both operands read as 4x256B dense runs from the
// packed layout; 2-deep static double-register prefetch (unroll-by-2).
// MODE 0: A=xp,  out1 = q bf16 (B,H,512,64) * (0.125*log2e)
// MODE 1: A=mp,  out1/out2 = PACKED K / V fragments
// MODE 2: A generated from po0+po1 scaled by 1/(dn0+dn1)  (fused combine);
//         out1 = fp32 (4096x1024) + bias
template <int MODE>
__global__ void __launch_bounds__(256) k_gemm(const unsigned short* __restrict__ Ap,
                                              const unsigned short* __restrict__ Bp,
                                              const float* __restrict__ bias,
                                              void* __restrict__ out1,
                                              void* __restrict__ out2,
                                              const float* __restrict__ po,
                                              const float* __restrict__ dn,
                                              int M) {
  const int tid = threadIdx.x, lane = tid & 63, wid = tid >> 6;
  const int grp = lane >> 4, lm = lane & 15;
  constexpr int NBY = (MODE == 1) ? 16 : 8;
  constexpr int NWG = (MODE == 1) ? 94 * 16 : 32 * 8;
  constexpr int CPX = NWG / 8;
  constexpr int NKT = 16;
  const int bid = blockIdx.x;
  const int logical = (bid & 7) * CPX + (bid >> 3);   // XCD-chunked (bijective)
  const int mblk = logical / NBY, nblk = logical % NBY;
  const int m0 = mblk * 128, n0 = nblk * 128;
  const int wm = (wid >> 1) * 64, wn = (wid & 1) * 64;

  const unsigned short* ab = Ap + (size_t)mblk * 131072 + grp * 1024 + (wm + lm) * 8;
  const unsigned short* bb = Bp + (size_t)nblk * 131072 + grp * 1024 + (wn + lm) * 8;

  f32x4 acc[4][4] = {};
  short8 aA[4][2], bA[4][2], aB[4][2], bB[4][2];

#define LOADB_(dst, kt)                                                          \
  {                                                                              \
    _Pragma("unroll") for (int n = 0; n < 4; ++n)                                \
        _Pragma("unroll") for (int ks = 0; ks < 2; ++ks)                         \
            dst[n][ks] = *reinterpret_cast<const short8*>(                       \
                bb + ((kt) * 2 + ks) * 4096 + n * 128);                          \
  }
#define LOADA_(dst, kt)                                                          \
  {                                                                              \
    if (MODE != 2) {                                                             \
      _Pragma("unroll") for (int m = 0; m < 4; ++m)                              \
          _Pragma("unroll") for (int ks = 0; ks < 2; ++ks)                       \
              dst[m][ks] = *reinterpret_cast<const short8*>(                     \
                  ab + ((kt) * 2 + ks) * 4096 + m * 128);                        \
    } else {                                                                     \
      _Pragma("unroll") for (int m = 0; m < 4; ++m) {                            \
        int row = m0 + wm + m * 16 + lm;  /* r9 bug: m0 was missing */           \
        float inv = 1.0f / (dn[row * 16 + (kt)] + dn[65536 + row * 16 + (kt)]);  \
        _Pragma("unroll") for (int ks = 0; ks < 2; ++ks) {                       \
          const float* p0 = po + (size_t)row * 1024 + (kt) * 64 + ks * 32 + grp * 8; \
          const float* p1 = p0 + 4194304;                                        \
          float4 x0 = *reinterpret_cast<const float4*>(p0);                      \
          float4 x1 = *reinterpret_cast<const float4*>(p0 + 4);                  \
          float4 y0 = *reinterpret_cast<const float4*>(p1);                      \
          float4 y1 = *reinterpret_cast<const float4*>(p1 + 4);                  \
          float v[8] = {(x0.x + y0.x) * inv, (x0.y + y0.y) * inv,                \
                        (x0.z + y0.z) * inv, (x0.w + y0.w) * inv,                \
                        (x1.x + y1.x) * inv, (x1.y + y1.y) * inv,                \
                        (x1.z + y1.z) * inv, (x1.w + y1.w) * inv};               \
          dst[m][ks] = pack8(v);                                                 \
        }                                                                        \
      }                                                                          \
    }                                                                            \
  }
#define MFMA_(a, b)                                                              \
  {                                                                              \
    _Pragma("unroll") for (int m = 0; m < 4; ++m)                                \
        _Pragma("unroll") for (int n = 0; n < 4; ++n)                            \
            _Pragma("unroll") for (int ks = 0; ks < 2; ++ks)                     \
                acc[m][n] = __builtin_amdgcn_mfma_f32_16x16x32_bf16(             \
                    a[m][ks], b[n][ks], acc[m][n], 0, 0, 0);                     \
  }

  LOADA_(aA, 0);
  LOADB_(bA, 0);
  for (int kt2 = 0; kt2 < NKT / 2; ++kt2) {
    const int ktb = 2 * kt2 + 1;
    LOADA_(aB, ktb);
    LOADB_(bB, ktb);
    MFMA_(aA, bA);
    if (ktb + 1 < NKT) {
      LOADA_(aA, ktb + 1);
      LOADB_(bA, ktb + 1);
    }
    MFMA_(aB, bB);
  }
#undef LOADA_
#undef LOADB_
#undef MFMA_

#pragma unroll
  for (int m = 0; m < 4; ++m) {
    int rbase = m0 + wm + m * 16 + grp * 4;
#pragma unroll
    for (int n = 0; n < 4; ++n) {
      int cg = n0 + wn + n * 16 + lm;
      float bs = bias[cg];
#pragma unroll
      for (int r = 0; r < 4; ++r) {
        int row = rbase + r;
        float v = acc[m][n][r] + bs;
        if (MODE == 0) {
          v *= 0.180336884f;  // DK^-0.5 * log2(e)  (softmax runs in base-2)
          int b = row >> 9, t1 = row & 511, h = cg >> 6, dk = cg & 63;
          ((unsigned short*)out1)[(((size_t)b * 16 + h) * 512 + t1) * 64 + dk] = bf16_rne(v);
        } else if (MODE == 1) {
          if (row < M) {
            int b = row / 1500, t2 = row - b * 1500;
            if (cg < 1024) {
              int h = cg >> 6, dk = cg & 63;
              int head = b * 16 + h;
              size_t idx = ((size_t)(head * 24 + (t2 >> 6)) * 8 + (dk >> 3)) * 512 +
                           (t2 & 63) * 8 + (dk & 7);
              ((unsigned short*)out1)[idx] = bf16_rne(v);
            } else {
              int h = (cg - 1024) >> 6, dk = (cg - 1024) & 63;
              int head = b * 16 + h;
              size_t idx = ((size_t)(head * 24 + (t2 >> 6)) * 8 + ((t2 >> 3) & 7)) * 512 +
                           dk * 8 + (t2 & 7);
              ((unsigned short*)out2)[idx] = bf16_rne(v);
            }
          }
        } else {
          ((float*)out1)[(size_t)row * 1024 + cg] = v;
        }
      }
    }
  }
}

// ---------------- flash attention, split-KV x2, packed fragment loads --------
// (unchanged — fixed-max base-2 softmax, barrier-free)
__global__ void __launch_bounds__(256) k_attn(const unsigned short* __restrict__ Q,
                                              const unsigned short* __restrict__ PK,
                                              const unsigned short* __restrict__ PV,
                                              const int* __restrict__ mask,
                                              float* __restrict__ po,
                                              float* __restrict__ dn) {
  __shared__ unsigned short Ps[4][16 * 64];
  const int tid = threadIdx.x, lane = tid & 63, wid = tid >> 6;
  const int grp = lane >> 4, lm = lane & 15;
  const int bid = blockIdx.x;                       // 2048
  const int logical = (bid & 7) * 256 + (bid >> 3);
  const int head = logical >> 4, qt = (logical >> 1) & 7, half = logical & 1;
  const int b = head >> 4, h = head & 15;
  const int kt0 = half * 12;

  const unsigned short* qbase = Q + ((size_t)head * 512 + qt * 64) * 64;
  const unsigned short* kf = PK + (size_t)head * 98304 + grp * 512 + lm * 8;
  const unsigned short* vf = PV + (size_t)head * 98304 + grp * 512 + lm * 8;
  const int* mrow = mask + b * 1500;

  short8 aq[2];
#pragma unroll
  for (int ks = 0; ks < 2; ++ks)
    aq[ks] = *reinterpret_cast<const short8*>(qbase + (wid * 16 + lm) * 64 + ks * 32 + grp * 8);

  unsigned long long mlo = 0ull;
#pragma unroll
  for (int i = 0; i < 48; ++i) {
    int col = (kt0 + (i >> 2)) * 64 + (i & 3) * 16 + lm;
    unsigned int ok = (col < 1500) ? (mrow[col] != 0 ? 1u : 0u) : 0u;
    mlo |= (unsigned long long)ok << i;
  }

  f32x4 O[4] = {};
  f32x4 O4 = {0.f, 0.f, 0.f, 0.f};
  const short8 onesb = {(short)0x3F80, (short)0x3F80, (short)0x3F80, (short)0x3F80,
                        (short)0x3F80, (short)0x3F80, (short)0x3F80, (short)0x3F80};

  short8 bk[4][2];
#pragma unroll
  for (int n = 0; n < 4; ++n)
#pragma unroll
    for (int ks = 0; ks < 2; ++ks)
      bk[n][ks] = *reinterpret_cast<const short8*>(kf + (size_t)kt0 * 4096 + ks * 2048 + n * 128);

  for (int kt = kt0; kt < kt0 + 12; ++kt) {
    short8 bv[4][2];
#pragma unroll
    for (int n2 = 0; n2 < 4; ++n2)
#pragma unroll
      for (int ks = 0; ks < 2; ++ks)
        bv[n2][ks] = *reinterpret_cast<const short8*>(vf + (size_t)kt * 4096 + ks * 2048 + n2 * 128);

    f32x4 s[4];
#pragma unroll
    for (int n = 0; n < 4; ++n) {
      s[n] = f32x4{0.f, 0.f, 0.f, 0.f};
#pragma unroll
      for (int ks = 0; ks < 2; ++ks)
        s[n] = __builtin_amdgcn_mfma_f32_16x16x32_bf16(aq[ks], bk[n][ks], s[n], 0, 0, 0);
    }

    if (kt < kt0 + 11) {
#pragma unroll
      for (int n = 0; n < 4; ++n)
#pragma unroll
        for (int ks = 0; ks < 2; ++ks)
          bk[n][ks] = *reinterpret_cast<const short8*>(
              kf + (size_t)(kt + 1) * 4096 + ks * 2048 + n * 128);
    }

    unsigned int nib = (unsigned int)mlo & 15u;
    mlo >>= 4;
    float mb4[4];
#pragma unroll
    for (int n = 0; n < 4; ++n) mb4[n] = (nib >> n) & 1u ? -8.0f : -3.0e38f;
#pragma unroll
    for (int n = 0; n < 4; ++n)
#pragma unroll
      for (int r = 0; r < 4; ++r) s[n][r] = exp2f(s[n][r] + mb4[n]);

#pragma unroll
    for (int n = 0; n < 4; ++n)
#pragma unroll
      for (int r = 0; r < 4; ++r) {
        int prow = grp * 4 + r;
        int pb = (n * 16 + lm) * 2;
        Ps[wid][prow * 64 + ((pb ^ ((prow & 7) << 4)) >> 1)] = bf16_rne(s[n][r]);
      }
    short8 pa[2];
#pragma unroll
    for (int ks = 0; ks < 2; ++ks) {
      int off = (ks * 64 + grp * 16) ^ ((lm & 7) << 4);
      pa[ks] = *reinterpret_cast<const short8*>(&Ps[wid][lm * 64 + (off >> 1)]);
    }

#pragma unroll
    for (int n2 = 0; n2 < 4; ++n2)
#pragma unroll
      for (int ks = 0; ks < 2; ++ks)
        O[n2] = __builtin_amdgcn_mfma_f32_16x16x32_bf16(pa[ks], bv[n2][ks], O[n2], 0, 0, 0);
#pragma unroll
    for (int ks = 0; ks < 2; ++ks)
      O4 = __builtin_amdgcn_mfma_f32_16x16x32_bf16(pa[ks], onesb, O4, 0, 0, 0);
  }

  float* orow = po + (size_t)half * 4194304 +
                ((size_t)(b * 512 + qt * 64 + wid * 16 + grp * 4)) * 1024 + h * 64;
#pragma unroll
  for (int r = 0; r < 4; ++r)
#pragma unroll
    for (int n2 = 0; n2 < 4; ++n2)
      orow[r * 1024 + n2 * 16 + lm] = O[n2][r];
  if (lm == 0) {
    int t1g = b * 512 + qt * 64 + wid * 16 + grp * 4;
#pragma unroll
    for (int r = 0; r < 4; ++r)
      dn[half * 65536 + (t1g + r) * 16 + h] = O4[r];
  }
}

// ---------------- launch -----------------------------------------------------
extern "C" void kernel_launch(void* const* d_in, const int* in_sizes, int n_in,
                              void* d_out, int out_size, void* d_ws, size_t ws_size,
                              hipStream_t stream) {
  const float* x = (const float*)d_in[0];
  const float* mem = (const float*)d_in[1];
  const int* mask = (const int*)d_in[2];
  const float* Wq = (const float*)d_in[3];
  const float* bq = (const float*)d_in[4];
  const float* Wkv = (const float*)d_in[5];
  const float* bkv = (const float*)d_in[6];
  const float* Wout = (const float*)d_in[7];
  const float* bout = (const float*)d_in[8];

  uint8_t* w = (uint8_t*)d_ws;
  unsigned short* xbp  = (unsigned short*)(w);                // packed x, 8,388,608 B (dead after q-GEMM)
  unsigned short* mbp  = (unsigned short*)(w + 8388608);      // packed mem, 24,641,536 B (dead after kv-GEMM)
  unsigned short* wqp  = (unsigned short*)(w + 33030144);     // packed Wq^T, 2,097,152 (dead after q-GEMM)
  unsigned short* wkvp = (unsigned short*)(w + 35127296);     // packed Wkv^T, 4,194,304 (dead after kv-GEMM)
  unsigned short* wop  = (unsigned short*)(w + 39321600);     // packed Wout^T, 2,097,152 (live to end)
  unsigned short* qb   = (unsigned short*)(w + 41418752);     // q (B,H,512,64), 8,388,608
  unsigned short* kb   = (unsigned short*)(w + 49807360);     // packed K frags, 25,165,824
  unsigned short* vtb  = (unsigned short*)(w + 74973184);     // packed V frags, 25,165,824
  float* po            = (float*)(w);                         // [2][4096][1024] fp32, 32MB (overlays dead xbp/mbp/wqp)
  float* dn            = (float*)(w + 35127296);              // [2][4096][16] fp32 (overlays dead wkvp)

  k_prep<<<11264, 256, 0, stream>>>(x, mem, Wq, Wkv, Wout, xbp, mbp, wqp, wkvp, wop, kb, vtb);
  k_gemm<0><<<256, 256, 0, stream>>>(xbp, wqp, bq, qb, nullptr, nullptr, nullptr, 4096);
  k_gemm<1><<<1504, 256, 0, stream>>>(mbp, wkvp, bkv, kb, vtb, nullptr, nullptr, 12000);
  k_attn<<<2048, 256, 0, stream>>>(qb, kb, vtb, mask, po, dn);
  k_gemm<2><<<256, 256, 0, stream>>>(nullptr, wop, bout, d_out, nullptr, po, dn, 4096);
}

// Round 12
// 262.054 us; speedup vs baseline: 1.0478x; 1.0478x over previous
//
#include <hip/hip_runtime.h>
#include <cstdint>
#include <cstddef>

typedef __attribute__((ext_vector_type(8))) short short8;
typedef __attribute__((ext_vector_type(4))) float f32x4;

typedef __attribute__((address_space(3))) unsigned int lds_u32;
typedef const __attribute__((address_space(1))) unsigned int glb_u32;

__device__ __forceinline__ void gl_lds16(const void* g, void* l) {
  __builtin_amdgcn_global_load_lds((glb_u32*)g, (lds_u32*)l, 16, 0, 0);
}

__device__ __forceinline__ unsigned short bf16_rne(float f) {
  unsigned int u = __float_as_uint(f);
  u += 0x7FFFu + ((u >> 16) & 1u);
  return (unsigned short)(u >> 16);
}

__device__ __forceinline__ short8 pack8(const float* v) {
  short8 r;
#pragma unroll
  for (int e = 0; e < 8; ++e) r[e] = (short)bf16_rne(v[e]);
  return r;
}

// ---------------- fused prep -------------------------------------------------
// [0,2048)      x fp32->bf16 row-major
// [2048,8048)   mem fp32->bf16 row-major
// [8048,8304)   Wq^T  (1024x1024) row-major N x K
// [8304,8816)   Wkv^T (2048x1024) row-major N x K
// [8816,9328)   Wout packed fragment-major [nblk][kt][ks][grp][rowN][e8]
// [9328,10480)  zero T2-pad entries of packed K/V
__device__ __forceinline__ void cvt_body(const float* __restrict__ in,
                                         unsigned short* __restrict__ out,
                                         int i, int n8) {
  if (i >= n8) return;
  float4 a = reinterpret_cast<const float4*>(in)[2 * i];
  float4 b = reinterpret_cast<const float4*>(in)[2 * i + 1];
  float v[8] = {a.x, a.y, a.z, a.w, b.x, b.y, b.z, b.w};
  reinterpret_cast<short8*>(out)[i] = pack8(v);
}

__global__ void __launch_bounds__(256) k_prep(const float* __restrict__ x,
                                              const float* __restrict__ mem,
                                              const float* __restrict__ Wq,
                                              const float* __restrict__ Wkv,
                                              const float* __restrict__ Wout,
                                              unsigned short* __restrict__ xb,
                                              unsigned short* __restrict__ mb,
                                              unsigned short* __restrict__ wqT,
                                              unsigned short* __restrict__ wkvT,
                                              unsigned short* __restrict__ wop,
                                              unsigned short* __restrict__ pk,
                                              unsigned short* __restrict__ pv) {
  __shared__ float t[64][65];
  const int bid = blockIdx.x, tid = threadIdx.x;
  if (bid < 2048) {
    cvt_body(x, xb, bid * 256 + tid, 524288);
  } else if (bid < 8048) {
    cvt_body(mem, mb, (bid - 2048) * 256 + tid, 1536000);
  } else if (bid < 8816) {
    const float* W; unsigned short* WT; int C, bid2, bx, by;
    if (bid < 8304) { W = Wq;  WT = wqT;  C = 1024; bid2 = bid - 8048; bx = bid2 & 15; by = bid2 >> 4; }
    else            { W = Wkv; WT = wkvT; C = 2048; bid2 = bid - 8304; bx = bid2 & 31; by = bid2 >> 5; }
    const int c0 = bx * 64, r0 = by * 64;
    const int lr = tid >> 6, lc = tid & 63;
#pragma unroll
    for (int i = 0; i < 16; ++i)
      t[i * 4 + lr][lc] = W[(size_t)(r0 + i * 4 + lr) * C + c0 + lc];
    __syncthreads();
#pragma unroll
    for (int i = 0; i < 16; ++i) {
      int ro = i * 4 + lr;
      WT[(size_t)(c0 + ro) * 1024 + r0 + lc] = bf16_rne(t[lc][ro]);
    }
  } else if (bid < 9328) {
    int w0 = (bid - 8816) * 256 + tid;       // 131072 total
    int rowN = w0 & 127; int tt = w0 >> 7;
    int grp = tt & 3; tt >>= 2;
    int ks = tt & 1; tt >>= 1;
    int kt = tt & 15; int nblk = tt >> 4;
    int n = nblk * 128 + rowN;
    int k0 = kt * 64 + ks * 32 + grp * 8;
    float v[8];
#pragma unroll
    for (int e = 0; e < 8; ++e) v[e] = Wout[(size_t)(k0 + e) * 1024 + n];
    *reinterpret_cast<short8*>(wop + (size_t)w0 * 8) = pack8(v);
  } else {
    int i = (bid - 9328) * 256 + tid;        // 128*36*64 = 294912
    if (i >= 128 * 36 * 64) return;
    int head = i / (36 * 64);
    int rem = i - head * (36 * 64);
    int t2 = rem / 64 + 1500;
    int dk = rem & 63;
    size_t ik = ((size_t)(head * 24 + 23) * 8 + (dk >> 3)) * 512 + (t2 & 63) * 8 + (dk & 7);
    size_t iv = ((size_t)(head * 24 + 23) * 8 + ((t2 >> 3) & 7)) * 512 + dk * 8 + (t2 & 7);
    pk[ik] = 0;
    pv[iv] = 0;
  }
}

// ---------------- r7 single-buffer gl_lds GEMM body (128x128, BK=64) ---------
// MODE 0: q epilogue -> q bf16 (B,H,512,64) * (0.125*log2e)
// MODE 1: kv epilogue -> PACKED fragment-major K and V
template <int MODE>
__device__ __forceinline__ void gemm_body(unsigned short* As, unsigned short* Bs,
                                          const unsigned short* __restrict__ A,
                                          const unsigned short* __restrict__ BT,
                                          const float* __restrict__ bias,
                                          void* __restrict__ out1,
                                          void* __restrict__ out2,
                                          int M, int bid) {
  const int tid = threadIdx.x;
  const int lane = tid & 63;
  const int wid = tid >> 6;
  const int grp = lane >> 4, lm = lane & 15;
  constexpr int K = 1024;
  constexpr int NBY = (MODE == 1) ? 16 : 8;
  constexpr int NWG = (MODE == 1) ? 1504 : 256;
  constexpr int CPX = NWG / 8;
  const int logical = (bid & 7) * CPX + (bid >> 3);   // XCD-chunked (bijective)
  const int m0 = (logical / NBY) * 128, n0 = (logical % NBY) * 128;
  const int wm = (wid >> 1) * 64, wn = (wid & 1) * 64;
  const int srow = tid >> 3;
  const int sx = ((tid & 7) * 16) ^ ((srow & 7) << 4);  // pre-swizzled src byte col

  f32x4 acc[4][4] = {};
  const int nkt = K >> 6;
  for (int kt = 0; kt < nkt; ++kt) {
    __syncthreads();   // prior iteration's fragment reads complete
#pragma unroll
    for (int c = 0; c < 4; ++c) {
      int row = c * 32 + srow;
      int ra = m0 + row; if (ra > M - 1) ra = M - 1;
      gl_lds16(A + (size_t)ra * K + kt * 64 + (sx >> 1), As + c * 2048 + tid * 8);
      gl_lds16(BT + (size_t)(n0 + row) * K + kt * 64 + (sx >> 1), Bs + c * 2048 + tid * 8);
    }
    __syncthreads();   // stage drained -> LDS ready

    short8 af[4][2], bfr[4][2];
#pragma unroll
    for (int m = 0; m < 4; ++m)
#pragma unroll
      for (int ks = 0; ks < 2; ++ks) {
        int row = wm + m * 16 + lm;
        int off = (ks * 64 + grp * 16) ^ ((row & 7) << 4);
        af[m][ks] = *reinterpret_cast<const short8*>(&As[row * 64 + (off >> 1)]);
      }
#pragma unroll
    for (int n = 0; n < 4; ++n)
#pragma unroll
      for (int ks = 0; ks < 2; ++ks) {
        int row = wn + n * 16 + lm;
        int off = (ks * 64 + grp * 16) ^ ((row & 7) << 4);
        bfr[n][ks] = *reinterpret_cast<const short8*>(&Bs[row * 64 + (off >> 1)]);
      }
#pragma unroll
    for (int m = 0; m < 4; ++m)
#pragma unroll
      for (int n = 0; n < 4; ++n)
#pragma unroll
        for (int ks = 0; ks < 2; ++ks)
          acc[m][n] = __builtin_amdgcn_mfma_f32_16x16x32_bf16(af[m][ks], bfr[n][ks],
                                                              acc[m][n], 0, 0, 0);
  }

#pragma unroll
  for (int m = 0; m < 4; ++m) {
    int rbase = m0 + wm + m * 16 + grp * 4;
#pragma unroll
    for (int n = 0; n < 4; ++n) {
      int cg = n0 + wn + n * 16 + lm;
      float bs = bias[cg];
#pragma unroll
      for (int r = 0; r < 4; ++r) {
        int row = rbase + r;
        float v = acc[m][n][r] + bs;
        if (MODE == 0) {
          v *= 0.180336884f;  // DK^-0.5 * log2(e)
          int b = row >> 9, t1 = row & 511, h = cg >> 6, dk = cg & 63;
          ((unsigned short*)out1)[(((size_t)b * 16 + h) * 512 + t1) * 64 + dk] = bf16_rne(v);
        } else {
          if (row < M) {
            int b = row / 1500, t2 = row - b * 1500;
            if (cg < 1024) {
              int h = cg >> 6, dk = cg & 63;
              int head = b * 16 + h;
              size_t idx = ((size_t)(head * 24 + (t2 >> 6)) * 8 + (dk >> 3)) * 512 +
                           (t2 & 63) * 8 + (dk & 7);
              ((unsigned short*)out1)[idx] = bf16_rne(v);
            } else {
              int h = (cg - 1024) >> 6, dk = (cg - 1024) & 63;
              int head = b * 16 + h;
              size_t idx = ((size_t)(head * 24 + (t2 >> 6)) * 8 + ((t2 >> 3) & 7)) * 512 +
                           dk * 8 + (t2 & 7);
              ((unsigned short*)out2)[idx] = bf16_rne(v);
            }
          }
        }
      }
    }
  }
}

// merged q + kv projection launch: blocks [0,1504) = kv, [1504,1760) = q
__global__ void __launch_bounds__(256) k_gemm01(const unsigned short* __restrict__ xb,
                                                const unsigned short* __restrict__ wqT,
                                                const float* __restrict__ bq,
                                                unsigned short* __restrict__ qb,
                                                const unsigned short* __restrict__ mb,
                                                const unsigned short* __restrict__ wkvT,
                                                const float* __restrict__ bkv,
                                                unsigned short* __restrict__ kb,
                                                unsigned short* __restrict__ vtb) {
  __shared__ unsigned short As[128 * 64];
  __shared__ unsigned short Bs[128 * 64];
  if (blockIdx.x < 1504)
    gemm_body<1>(As, Bs, mb, wkvT, bkv, kb, vtb, 12000, blockIdx.x);
  else
    gemm_body<0>(As, Bs, xb, wqT, bq, qb, nullptr, 4096, blockIdx.x - 1504);
}

// ---------------- fused combine + out-GEMM (barrier-free, packed Wout) -------
// A generated from po0+po1 scaled by 1/(dn0+dn1); B = packed wop fragments.
__global__ void __launch_bounds__(256) k_gemm2(const unsigned short* __restrict__ Bp,
                                               const float* __restrict__ bias,
                                               float* __restrict__ out1,
                                               const float* __restrict__ po,
                                               const float* __restrict__ dn) {
  const int tid = threadIdx.x, lane = tid & 63, wid = tid >> 6;
  const int grp = lane >> 4, lm = lane & 15;
  constexpr int NKT = 16;
  const int bid = blockIdx.x;                         // 256
  const int logical = (bid & 7) * 32 + (bid >> 3);
  const int mblk = logical >> 3, nblk = logical & 7;
  const int m0 = mblk * 128, n0 = nblk * 128;
  const int wm = (wid >> 1) * 64, wn = (wid & 1) * 64;

  const unsigned short* bb = Bp + (size_t)nblk * 131072 + grp * 1024 + (wn + lm) * 8;

  f32x4 acc[4][4] = {};
  short8 aA[4][2], bA[4][2], aB[4][2], bB[4][2];

#define LOADB_(dst, kt)                                                          \
  {                                                                              \
    _Pragma("unroll") for (int n = 0; n < 4; ++n)                                \
        _Pragma("unroll") for (int ks = 0; ks < 2; ++ks)                         \
            dst[n][ks] = *reinterpret_cast<const short8*>(                       \
                bb + ((kt) * 2 + ks) * 4096 + n * 128);                          \
  }
#define LOADA_(dst, kt)                                                          \
  {                                                                              \
    _Pragma("unroll") for (int m = 0; m < 4; ++m) {                              \
      int row = m0 + wm + m * 16 + lm;                                           \
      float inv = 1.0f / (dn[row * 16 + (kt)] + dn[65536 + row * 16 + (kt)]);    \
      _Pragma("unroll") for (int ks = 0; ks < 2; ++ks) {                         \
        const float* p0 = po + (size_t)row * 1024 + (kt) * 64 + ks * 32 + grp * 8; \
        const float* p1 = p0 + 4194304;                                          \
        float4 x0 = *reinterpret_cast<const float4*>(p0);                        \
        float4 x1 = *reinterpret_cast<const float4*>(p0 + 4);                    \
        float4 y0 = *reinterpret_cast<const float4*>(p1);                        \
        float4 y1 = *reinterpret_cast<const float4*>(p1 + 4);                    \
        float v[8] = {(x0.x + y0.x) * inv, (x0.y + y0.y) * inv,                  \
                      (x0.z + y0.z) * inv, (x0.w + y0.w) * inv,                  \
                      (x1.x + y1.x) * inv, (x1.y + y1.y) * inv,                  \
                      (x1.z + y1.z) * inv, (x1.w + y1.w) * inv};                 \
        dst[m][ks] = pack8(v);                                                   \
      }                                                                          \
    }                                                                            \
  }
#define MFMA_(a, b)                                                              \
  {                                                                              \
    _Pragma("unroll") for (int m = 0; m < 4; ++m)                                \
        _Pragma("unroll") for (int n = 0; n < 4; ++n)                            \
            _Pragma("unroll") for (int ks = 0; ks < 2; ++ks)                     \
                acc[m][n] = __builtin_amdgcn_mfma_f32_16x16x32_bf16(             \
                    a[m][ks], b[n][ks], acc[m][n], 0, 0, 0);                     \
  }

  LOADA_(aA, 0);
  LOADB_(bA, 0);
  for (int kt2 = 0; kt2 < NKT / 2; ++kt2) {
    const int ktb = 2 * kt2 + 1;
    LOADA_(aB, ktb);
    LOADB_(bB, ktb);
    MFMA_(aA, bA);
    if (ktb + 1 < NKT) {
      LOADA_(aA, ktb + 1);
      LOADB_(bA, ktb + 1);
    }
    MFMA_(aB, bB);
  }
#undef LOADA_
#undef LOADB_
#undef MFMA_

#pragma unroll
  for (int m = 0; m < 4; ++m) {
    int rbase = m0 + wm + m * 16 + grp * 4;
#pragma unroll
    for (int n = 0; n < 4; ++n) {
      int cg = n0 + wn + n * 16 + lm;
      float bs = bias[cg];
#pragma unroll
      for (int r = 0; r < 4; ++r)
        out1[(size_t)(rbase + r) * 1024 + cg] = acc[m][n][r] + bs;
    }
  }
}

// ---------------- flash attention, split-KV x2, packed fragment loads --------
// (unchanged — fixed-max base-2 softmax, barrier-free)
__global__ void __launch_bounds__(256) k_attn(const unsigned short* __restrict__ Q,
                                              const unsigned short* __restrict__ PK,
                                              const unsigned short* __restrict__ PV,
                                              const int* __restrict__ mask,
                                              float* __restrict__ po,
                                              float* __restrict__ dn) {
  __shared__ unsigned short Ps[4][16 * 64];
  const int tid = threadIdx.x, lane = tid & 63, wid = tid >> 6;
  const int grp = lane >> 4, lm = lane & 15;
  const int bid = blockIdx.x;                       // 2048
  const int logical = (bid & 7) * 256 + (bid >> 3);
  const int head = logical >> 4, qt = (logical >> 1) & 7, half = logical & 1;
  const int b = head >> 4, h = head & 15;
  const int kt0 = half * 12;

  const unsigned short* qbase = Q + ((size_t)head * 512 + qt * 64) * 64;
  const unsigned short* kf = PK + (size_t)head * 98304 + grp * 512 + lm * 8;
  const unsigned short* vf = PV + (size_t)head * 98304 + grp * 512 + lm * 8;
  const int* mrow = mask + b * 1500;

  short8 aq[2];
#pragma unroll
  for (int ks = 0; ks < 2; ++ks)
    aq[ks] = *reinterpret_cast<const short8*>(qbase + (wid * 16 + lm) * 64 + ks * 32 + grp * 8);

  unsigned long long mlo = 0ull;
#pragma unroll
  for (int i = 0; i < 48; ++i) {
    int col = (kt0 + (i >> 2)) * 64 + (i & 3) * 16 + lm;
    unsigned int ok = (col < 1500) ? (mrow[col] != 0 ? 1u : 0u) : 0u;
    mlo |= (unsigned long long)ok << i;
  }

  f32x4 O[4] = {};
  f32x4 O4 = {0.f, 0.f, 0.f, 0.f};
  const short8 onesb = {(short)0x3F80, (short)0x3F80, (short)0x3F80, (short)0x3F80,
                        (short)0x3F80, (short)0x3F80, (short)0x3F80, (short)0x3F80};

  short8 bk[4][2];
#pragma unroll
  for (int n = 0; n < 4; ++n)
#pragma unroll
    for (int ks = 0; ks < 2; ++ks)
      bk[n][ks] = *reinterpret_cast<const short8*>(kf + (size_t)kt0 * 4096 + ks * 2048 + n * 128);

  for (int kt = kt0; kt < kt0 + 12; ++kt) {
    short8 bv[4][2];
#pragma unroll
    for (int n2 = 0; n2 < 4; ++n2)
#pragma unroll
      for (int ks = 0; ks < 2; ++ks)
        bv[n2][ks] = *reinterpret_cast<const short8*>(vf + (size_t)kt * 4096 + ks * 2048 + n2 * 128);

    f32x4 s[4];
#pragma unroll
    for (int n = 0; n < 4; ++n) {
      s[n] = f32x4{0.f, 0.f, 0.f, 0.f};
#pragma unroll
      for (int ks = 0; ks < 2; ++ks)
        s[n] = __builtin_amdgcn_mfma_f32_16x16x32_bf16(aq[ks], bk[n][ks], s[n], 0, 0, 0);
    }

    if (kt < kt0 + 11) {
#pragma unroll
      for (int n = 0; n < 4; ++n)
#pragma unroll
        for (int ks = 0; ks < 2; ++ks)
          bk[n][ks] = *reinterpret_cast<const short8*>(
              kf + (size_t)(kt + 1) * 4096 + ks * 2048 + n * 128);
    }

    unsigned int nib = (unsigned int)mlo & 15u;
    mlo >>= 4;
    float mb4[4];
#pragma unroll
    for (int n = 0; n < 4; ++n) mb4[n] = (nib >> n) & 1u ? -8.0f : -3.0e38f;
#pragma unroll
    for (int n = 0; n < 4; ++n)
#pragma unroll
      for (int r = 0; r < 4; ++r) s[n][r] = exp2f(s[n][r] + mb4[n]);

#pragma unroll
    for (int n = 0; n < 4; ++n)
#pragma unroll
      for (int r = 0; r < 4; ++r) {
        int prow = grp * 4 + r;
        int pb = (n * 16 + lm) * 2;
        Ps[wid][prow * 64 + ((pb ^ ((prow & 7) << 4)) >> 1)] = bf16_rne(s[n][r]);
      }
    short8 pa[2];
#pragma unroll
    for (int ks = 0; ks < 2; ++ks) {
      int off = (ks * 64 + grp * 16) ^ ((lm & 7) << 4);
      pa[ks] = *reinterpret_cast<const short8*>(&Ps[wid][lm * 64 + (off >> 1)]);
    }

#pragma unroll
    for (int n2 = 0; n2 < 4; ++n2)
#pragma unroll
      for (int ks = 0; ks < 2; ++ks)
        O[n2] = __builtin_amdgcn_mfma_f32_16x16x32_bf16(pa[ks], bv[n2][ks], O[n2], 0, 0, 0);
#pragma unroll
    for (int ks = 0; ks < 2; ++ks)
      O4 = __builtin_amdgcn_mfma_f32_16x16x32_bf16(pa[ks], onesb, O4, 0, 0, 0);
  }

  float* orow = po + (size_t)half * 4194304 +
                ((size_t)(b * 512 + qt * 64 + wid * 16 + grp * 4)) * 1024 + h * 64;
#pragma unroll
  for (int r = 0; r < 4; ++r)
#pragma unroll
    for (int n2 = 0; n2 < 4; ++n2)
      orow[r * 1024 + n2 * 16 + lm] = O[n2][r];
  if (lm == 0) {
    int t1g = b * 512 + qt * 64 + wid * 16 + grp * 4;
#pragma unroll
    for (int r = 0; r < 4; ++r)
      dn[half * 65536 + (t1g + r) * 16 + h] = O4[r];
  }
}

// ---------------- launch -----------------------------------------------------
extern "C" void kernel_launch(void* const* d_in, const int* in_sizes, int n_in,
                              void* d_out, int out_size, void* d_ws, size_t ws_size,
                              hipStream_t stream) {
  const float* x = (const float*)d_in[0];
  const float* mem = (const float*)d_in[1];
  const int* mask = (const int*)d_in[2];
  const float* Wq = (const float*)d_in[3];
  const float* bq = (const float*)d_in[4];
  const float* Wkv = (const float*)d_in[5];
  const float* bkv = (const float*)d_in[6];
  const float* Wout = (const float*)d_in[7];
  const float* bout = (const float*)d_in[8];

  uint8_t* w = (uint8_t*)d_ws;
  unsigned short* xb   = (unsigned short*)(w);                // 4096x1024 bf16 (dead after q-GEMM)
  unsigned short* mb   = (unsigned short*)(w + 8388608);      // 12000x1024 bf16 (dead after kv-GEMM)
  unsigned short* wqT  = (unsigned short*)(w + 32964608);     // 1024x1024 (dead after q-GEMM)
  unsigned short* wkvT = (unsigned short*)(w + 35061760);     // 2048x1024 (dead after kv-GEMM)
  unsigned short* wop  = (unsigned short*)(w + 39256064);     // packed Wout frags (live to end)
  unsigned short* qb   = (unsigned short*)(w + 41353216);     // q (B,H,512,64)
  unsigned short* kb   = (unsigned short*)(w + 49741824);     // packed K frags
  unsigned short* vtb  = (unsigned short*)(w + 74907648);     // packed V frags
  float* po            = (float*)(w);                         // [2][4096][1024] fp32 (overlays dead xb/mb/wqT-head)
  float* dn            = (float*)(w + 33554432);              // [2][4096][16] fp32 (overlays dead wqT/wkvT)

  k_prep<<<10480, 256, 0, stream>>>(x, mem, Wq, Wkv, Wout, xb, mb, wqT, wkvT, wop, kb, vtb);
  k_gemm01<<<1760, 256, 0, stream>>>(xb, wqT, bq, qb, mb, wkvT, bkv, kb, vtb);
  k_attn<<<2048, 256, 0, stream>>>(qb, kb, vtb, mask, po, dn);
  k_gemm2<<<256, 256, 0, stream>>>(wop, bout, (float*)d_out, po, dn);
}

// Round 13
// 222.285 us; speedup vs baseline: 1.2353x; 1.1789x over previous
//
#include <hip/hip_runtime.h>
#include <cstdint>
#include <cstddef>

typedef __attribute__((ext_vector_type(8))) short short8;
typedef __attribute__((ext_vector_type(4))) float f32x4;

typedef __attribute__((address_space(3))) unsigned int lds_u32;
typedef const __attribute__((address_space(1))) unsigned int glb_u32;

__device__ __forceinline__ void gl_lds16(const void* g, void* l) {
  __builtin_amdgcn_global_load_lds((glb_u32*)g, (lds_u32*)l, 16, 0, 0);
}

__device__ __forceinline__ unsigned short bf16_rne(float f) {
  unsigned int u = __float_as_uint(f);
  u += 0x7FFFu + ((u >> 16) & 1u);
  return (unsigned short)(u >> 16);
}

// ---------------- fused prep: converts + weight transposes + pad -------------
// block ranges:
//   [0,2048)      : x fp32 -> bf16            (524288 x 8)
//   [2048,8048)   : mem fp32 -> bf16          (1536000 x 8)
//   [8048,8304)   : Wq^T  (1024x1024)
//   [8304,8816)   : Wkv^T (1024x2048)
//   [8816,9072)   : Wout^T(1024x1024)
//   [9072,10224)  : zero T2-pad entries of packed K/V
__device__ __forceinline__ void cvt_body(const float* __restrict__ in,
                                         unsigned short* __restrict__ out,
                                         int i, int n8) {
  if (i >= n8) return;
  float4 a = reinterpret_cast<const float4*>(in)[2 * i];
  float4 b = reinterpret_cast<const float4*>(in)[2 * i + 1];
  short8 v;
  v[0] = (short)bf16_rne(a.x); v[1] = (short)bf16_rne(a.y);
  v[2] = (short)bf16_rne(a.z); v[3] = (short)bf16_rne(a.w);
  v[4] = (short)bf16_rne(b.x); v[5] = (short)bf16_rne(b.y);
  v[6] = (short)bf16_rne(b.z); v[7] = (short)bf16_rne(b.w);
  reinterpret_cast<short8*>(out)[i] = v;
}

__global__ void __launch_bounds__(256) k_prep(const float* __restrict__ x,
                                              const float* __restrict__ mem,
                                              const float* __restrict__ Wq,
                                              const float* __restrict__ Wkv,
                                              const float* __restrict__ Wout,
                                              unsigned short* __restrict__ xb,
                                              unsigned short* __restrict__ mb,
                                              unsigned short* __restrict__ wqT,
                                              unsigned short* __restrict__ wkvT,
                                              unsigned short* __restrict__ woutT,
                                              unsigned short* __restrict__ pk,
                                              unsigned short* __restrict__ pv) {
  __shared__ float t[64][65];
  const int bid = blockIdx.x, tid = threadIdx.x;
  if (bid < 2048) {
    cvt_body(x, xb, bid * 256 + tid, 524288);
  } else if (bid < 8048) {
    cvt_body(mem, mb, (bid - 2048) * 256 + tid, 1536000);
  } else if (bid < 9072) {
    const float* W; unsigned short* WT; int R = 1024, C; int bid2, bx, by;
    if (bid < 8304)      { W = Wq;   WT = wqT;   C = 1024; bid2 = bid - 8048; bx = bid2 & 15; by = bid2 >> 4; }
    else if (bid < 8816) { W = Wkv;  WT = wkvT;  C = 2048; bid2 = bid - 8304; bx = bid2 & 31; by = bid2 >> 5; }
    else                 { W = Wout; WT = woutT; C = 1024; bid2 = bid - 8816; bx = bid2 & 15; by = bid2 >> 4; }
    const int c0 = bx * 64, r0 = by * 64;
    const int lr = tid >> 6, lc = tid & 63;
#pragma unroll
    for (int i = 0; i < 16; ++i)
      t[i * 4 + lr][lc] = W[(size_t)(r0 + i * 4 + lr) * C + c0 + lc];
    __syncthreads();
#pragma unroll
    for (int i = 0; i < 16; ++i) {
      int ro = i * 4 + lr;
      WT[(size_t)(c0 + ro) * R + r0 + lc] = bf16_rne(t[lc][ro]);
    }
  } else {
    int i = (bid - 9072) * 256 + tid;   // 128*36*64 = 294912
    if (i >= 128 * 36 * 64) return;
    int head = i / (36 * 64);
    int rem = i - head * (36 * 64);
    int t2 = rem / 64 + 1500;
    int dk = rem & 63;
    size_t ik = ((size_t)(head * 24 + 23) * 8 + (dk >> 3)) * 512 + (t2 & 63) * 8 + (dk & 7);
    size_t iv = ((size_t)(head * 24 + 23) * 8 + ((t2 >> 3) & 7)) * 512 + dk * 8 + (t2 & 7);
    pk[ik] = 0;
    pv[iv] = 0;
  }
}

// ---------------- 128x128 bf16 MFMA GEMM, BK=64, single-buffer gl_lds --------
// (r7 body — best measured: kv = 113 us)
// 1D grid, XCD-chunked swizzle; global source pre-swizzled for linear LDS dest.
// MODE 0: q-projection epilogue -> q bf16 (B,H,512,64) * (0.125*log2e)
// MODE 1: kv epilogue -> PACKED fragment-major K and V
// MODE 2: fp32 out + bias
template <int MODE>
__global__ void __launch_bounds__(256) k_gemm(const unsigned short* __restrict__ A,
                                              const unsigned short* __restrict__ BT,
                                              const float* __restrict__ bias,
                                              void* __restrict__ out1,
                                              void* __restrict__ out2,
                                              int M, int K) {
  __shared__ unsigned short As[128 * 64];
  __shared__ unsigned short Bs[128 * 64];
  const int tid = threadIdx.x;
  const int lane = tid & 63;
  const int wid = tid >> 6;
  const int grp = lane >> 4, lm = lane & 15;

  constexpr int NBY = (MODE == 1) ? 16 : 8;
  constexpr int NWG = (MODE == 1) ? 94 * 16 : 32 * 8;
  constexpr int CPX = NWG / 8;
  const int bid = blockIdx.x;
  const int logical = (bid & 7) * CPX + (bid >> 3);   // XCD-chunked (bijective)
  const int m0 = (logical / NBY) * 128, n0 = (logical % NBY) * 128;

  const int wm = (wid >> 1) * 64, wn = (wid & 1) * 64;
  const int srow = tid >> 3;                            // 0..31
  const int sx = ((tid & 7) * 16) ^ ((srow & 7) << 4);  // pre-swizzled src byte col

  f32x4 acc[4][4] = {};

  const int nkt = K >> 6;
  for (int kt = 0; kt < nkt; ++kt) {
    __syncthreads();   // prior iteration's fragment reads complete
#pragma unroll
    for (int c = 0; c < 4; ++c) {
      int row = c * 32 + srow;
      int ra = m0 + row; if (ra > M - 1) ra = M - 1;
      gl_lds16(A + (size_t)ra * K + kt * 64 + (sx >> 1), As + c * 2048 + tid * 8);
      gl_lds16(BT + (size_t)(n0 + row) * K + kt * 64 + (sx >> 1), Bs + c * 2048 + tid * 8);
    }
    __syncthreads();   // stage drained -> LDS ready

    short8 af[4][2], bfr[4][2];
#pragma unroll
    for (int m = 0; m < 4; ++m)
#pragma unroll
      for (int ks = 0; ks < 2; ++ks) {
        int row = wm + m * 16 + lm;
        int off = (ks * 64 + grp * 16) ^ ((row & 7) << 4);
        af[m][ks] = *reinterpret_cast<const short8*>(&As[row * 64 + (off >> 1)]);
      }
#pragma unroll
    for (int n = 0; n < 4; ++n)
#pragma unroll
      for (int ks = 0; ks < 2; ++ks) {
        int row = wn + n * 16 + lm;
        int off = (ks * 64 + grp * 16) ^ ((row & 7) << 4);
        bfr[n][ks] = *reinterpret_cast<const short8*>(&Bs[row * 64 + (off >> 1)]);
      }
#pragma unroll
    for (int m = 0; m < 4; ++m)
#pragma unroll
      for (int n = 0; n < 4; ++n)
#pragma unroll
        for (int ks = 0; ks < 2; ++ks)
          acc[m][n] = __builtin_amdgcn_mfma_f32_16x16x32_bf16(af[m][ks], bfr[n][ks],
                                                              acc[m][n], 0, 0, 0);
  }

#pragma unroll
  for (int m = 0; m < 4; ++m) {
    int rbase = m0 + wm + m * 16 + grp * 4;
#pragma unroll
    for (int n = 0; n < 4; ++n) {
      int cg = n0 + wn + n * 16 + lm;
      float bs = bias[cg];
#pragma unroll
      for (int r = 0; r < 4; ++r) {
        int row = rbase + r;
        float v = acc[m][n][r] + bs;
        if (MODE == 0) {
          v *= 0.180336884f;  // DK^-0.5 * log2(e)  (softmax runs in base-2)
          int b = row >> 9, t1 = row & 511, h = cg >> 6, dk = cg & 63;
          ((unsigned short*)out1)[(((size_t)b * 16 + h) * 512 + t1) * 64 + dk] = bf16_rne(v);
        } else if (MODE == 1) {
          if (row < M) {
            int b = row / 1500, t2 = row - b * 1500;
            if (cg < 1024) {
              int h = cg >> 6, dk = cg & 63;
              int head = b * 16 + h;
              size_t idx = ((size_t)(head * 24 + (t2 >> 6)) * 8 + (dk >> 3)) * 512 +
                           (t2 & 63) * 8 + (dk & 7);
              ((unsigned short*)out1)[idx] = bf16_rne(v);
            } else {
              int h = (cg - 1024) >> 6, dk = (cg - 1024) & 63;
              int head = b * 16 + h;
              size_t idx = ((size_t)(head * 24 + (t2 >> 6)) * 8 + ((t2 >> 3) & 7)) * 512 +
                           dk * 8 + (t2 & 7);
              ((unsigned short*)out2)[idx] = bf16_rne(v);
            }
          }
        } else {
          ((float*)out1)[(size_t)row * 1024 + cg] = v;
        }
      }
    }
  }
}

// ---------------- flash attention, split-KV x2, packed fragment loads --------
// Q  : (B*H, 512, 64) bf16, pre-scaled by 0.125*log2e
// PK : packed K fragments (head, kt, s=ks*4+grp, r=kcol, 8) bf16, pad zeroed
// PV : packed V fragments (head, kt, s, r=dcol, 8) bf16, pad zeroed
// po : fp32 partial O [2][4096][1024]; dn: fp32 partial denom [2][4096][16]
// Fixed-max base-2 softmax (p = 2^(s-8)) -> split partials are purely additive.
__global__ void __launch_bounds__(256) k_attn(const unsigned short* __restrict__ Q,
                                              const unsigned short* __restrict__ PK,
                                              const unsigned short* __restrict__ PV,
                                              const int* __restrict__ mask,
                                              float* __restrict__ po,
                                              float* __restrict__ dn) {
  __shared__ unsigned short Ps[4][16 * 64];
  const int tid = threadIdx.x, lane = tid & 63, wid = tid >> 6;
  const int grp = lane >> 4, lm = lane & 15;
  const int bid = blockIdx.x;                       // 2048
  const int logical = (bid & 7) * 256 + (bid >> 3);
  const int head = logical >> 4, qt = (logical >> 1) & 7, half = logical & 1;
  const int b = head >> 4, h = head & 15;
  const int kt0 = half * 12;

  const unsigned short* qbase = Q + ((size_t)head * 512 + qt * 64) * 64;
  const unsigned short* kf = PK + (size_t)head * 98304 + grp * 512 + lm * 8;
  const unsigned short* vf = PV + (size_t)head * 98304 + grp * 512 + lm * 8;
  const int* mrow = mask + b * 1500;

  short8 aq[2];
#pragma unroll
  for (int ks = 0; ks < 2; ++ks)
    aq[ks] = *reinterpret_cast<const short8*>(qbase + (wid * 16 + lm) * 64 + ks * 32 + grp * 8);

  unsigned long long mlo = 0ull;
#pragma unroll
  for (int i = 0; i < 48; ++i) {
    int col = (kt0 + (i >> 2)) * 64 + (i & 3) * 16 + lm;
    unsigned int ok = (col < 1500) ? (mrow[col] != 0 ? 1u : 0u) : 0u;
    mlo |= (unsigned long long)ok << i;
  }

  f32x4 O[4] = {};
  f32x4 O4 = {0.f, 0.f, 0.f, 0.f};
  const short8 onesb = {(short)0x3F80, (short)0x3F80, (short)0x3F80, (short)0x3F80,
                        (short)0x3F80, (short)0x3F80, (short)0x3F80, (short)0x3F80};

  short8 bk[4][2];
#pragma unroll
  for (int n = 0; n < 4; ++n)
#pragma unroll
    for (int ks = 0; ks < 2; ++ks)
      bk[n][ks] = *reinterpret_cast<const short8*>(kf + (size_t)kt0 * 4096 + ks * 2048 + n * 128);

  for (int kt = kt0; kt < kt0 + 12; ++kt) {
    short8 bv[4][2];
#pragma unroll
    for (int n2 = 0; n2 < 4; ++n2)
#pragma unroll
      for (int ks = 0; ks < 2; ++ks)
        bv[n2][ks] = *reinterpret_cast<const short8*>(vf + (size_t)kt * 4096 + ks * 2048 + n2 * 128);

    f32x4 s[4];
#pragma unroll
    for (int n = 0; n < 4; ++n) {
      s[n] = f32x4{0.f, 0.f, 0.f, 0.f};
#pragma unroll
      for (int ks = 0; ks < 2; ++ks)
        s[n] = __builtin_amdgcn_mfma_f32_16x16x32_bf16(aq[ks], bk[n][ks], s[n], 0, 0, 0);
    }

    if (kt < kt0 + 11) {
#pragma unroll
      for (int n = 0; n < 4; ++n)
#pragma unroll
        for (int ks = 0; ks < 2; ++ks)
          bk[n][ks] = *reinterpret_cast<const short8*>(
              kf + (size_t)(kt + 1) * 4096 + ks * 2048 + n * 128);
    }

    unsigned int nib = (unsigned int)mlo & 15u;
    mlo >>= 4;
    float mb4[4];
#pragma unroll
    for (int n = 0; n < 4; ++n) mb4[n] = (nib >> n) & 1u ? -8.0f : -3.0e38f;
#pragma unroll
    for (int n = 0; n < 4; ++n)
#pragma unroll
      for (int r = 0; r < 4; ++r) s[n][r] = exp2f(s[n][r] + mb4[n]);

#pragma unroll
    for (int n = 0; n < 4; ++n)
#pragma unroll
      for (int r = 0; r < 4; ++r) {
        int prow = grp * 4 + r;
        int pb = (n * 16 + lm) * 2;
        Ps[wid][prow * 64 + ((pb ^ ((prow & 7) << 4)) >> 1)] = bf16_rne(s[n][r]);
      }
    short8 pa[2];
#pragma unroll
    for (int ks = 0; ks < 2; ++ks) {
      int off = (ks * 64 + grp * 16) ^ ((lm & 7) << 4);
      pa[ks] = *reinterpret_cast<const short8*>(&Ps[wid][lm * 64 + (off >> 1)]);
    }

#pragma unroll
    for (int n2 = 0; n2 < 4; ++n2)
#pragma unroll
      for (int ks = 0; ks < 2; ++ks)
        O[n2] = __builtin_amdgcn_mfma_f32_16x16x32_bf16(pa[ks], bv[n2][ks], O[n2], 0, 0, 0);
#pragma unroll
    for (int ks = 0; ks < 2; ++ks)
      O4 = __builtin_amdgcn_mfma_f32_16x16x32_bf16(pa[ks], onesb, O4, 0, 0, 0);
  }

  float* orow = po + (size_t)half * 4194304 +
                ((size_t)(b * 512 + qt * 64 + wid * 16 + grp * 4)) * 1024 + h * 64;
#pragma unroll
  for (int r = 0; r < 4; ++r)
#pragma unroll
    for (int n2 = 0; n2 < 4; ++n2)
      orow[r * 1024 + n2 * 16 + lm] = O[n2][r];
  if (lm == 0) {
    int t1g = b * 512 + qt * 64 + wid * 16 + grp * 4;
#pragma unroll
    for (int r = 0; r < 4; ++r)
      dn[half * 65536 + (t1g + r) * 16 + h] = O4[r];
  }
}

// ---------------- combine split-KV partials -> bf16 ctx ----------------------
__global__ void __launch_bounds__(256) k_comb(const float* __restrict__ po,
                                              const float* __restrict__ dn,
                                              unsigned short* __restrict__ ctx) {
  int idx = blockIdx.x * 256 + threadIdx.x;   // 524288 = 4096*128
  if (idx >= 524288) return;
  int row = idx >> 7, c8 = idx & 127;
  int col0 = c8 * 8, h = c8 >> 3;
  float d = dn[row * 16 + h] + dn[65536 + row * 16 + h];
  float inv = 1.0f / d;
  const float4* p0 = reinterpret_cast<const float4*>(po + (size_t)row * 1024 + col0);
  const float4* p1 = reinterpret_cast<const float4*>(po + 4194304 + (size_t)row * 1024 + col0);
  float4 a0 = p0[0], a1 = p0[1], b0 = p1[0], b1 = p1[1];
  short8 v;
  v[0] = (short)bf16_rne((a0.x + b0.x) * inv);
  v[1] = (short)bf16_rne((a0.y + b0.y) * inv);
  v[2] = (short)bf16_rne((a0.z + b0.z) * inv);
  v[3] = (short)bf16_rne((a0.w + b0.w) * inv);
  v[4] = (short)bf16_rne((a1.x + b1.x) * inv);
  v[5] = (short)bf16_rne((a1.y + b1.y) * inv);
  v[6] = (short)bf16_rne((a1.z + b1.z) * inv);
  v[7] = (short)bf16_rne((a1.w + b1.w) * inv);
  reinterpret_cast<short8*>(ctx)[idx] = v;
}

// ---------------- launch -----------------------------------------------------
extern "C" void kernel_launch(void* const* d_in, const int* in_sizes, int n_in,
                              void* d_out, int out_size, void* d_ws, size_t ws_size,
                              hipStream_t stream) {
  const float* x = (const float*)d_in[0];
  const float* mem = (const float*)d_in[1];
  const int* mask = (const int*)d_in[2];
  const float* Wq = (const float*)d_in[3];
  const float* bq = (const float*)d_in[4];
  const float* Wkv = (const float*)d_in[5];
  const float* bkv = (const float*)d_in[6];
  const float* Wout = (const float*)d_in[7];
  const float* bout = (const float*)d_in[8];

  uint8_t* w = (uint8_t*)d_ws;
  unsigned short* xb    = (unsigned short*)(w);               // 4096x1024  (dead after q-GEMM)
  unsigned short* mb    = (unsigned short*)(w + 8388608);     // 12000x1024 (dead after kv-GEMM)
  unsigned short* wqT   = (unsigned short*)(w + 32964608);    // dead after q-GEMM
  unsigned short* wkvT  = (unsigned short*)(w + 35061760);    // dead after kv-GEMM
  unsigned short* woutT = (unsigned short*)(w + 39256064);    // live until final GEMM
  unsigned short* qb    = (unsigned short*)(w + 41353216);    // q (B,H,512,64)
  unsigned short* kb    = (unsigned short*)(w + 49741824);    // packed K frags
  unsigned short* vtb   = (unsigned short*)(w + 74907648);    // packed V frags
  unsigned short* ctx   = (unsigned short*)(w + 100073472);   // 4096x1024
  float* po             = (float*)(w);                        // [2][4096][1024] fp32, 32MB (overlays dead xb/mb/wqT)
  float* dn             = (float*)(w + 33554432);             // [2][4096][16] fp32 (overlays dead wqT/wkvT)

  k_prep<<<10224, 256, 0, stream>>>(x, mem, Wq, Wkv, Wout, xb, mb, wqT, wkvT, woutT, kb, vtb);
  k_gemm<0><<<256, 256, 0, stream>>>(xb, wqT, bq, qb, nullptr, 4096, 1024);
  k_gemm<1><<<1504, 256, 0, stream>>>(mb, wkvT, bkv, kb, vtb, 12000, 1024);
  k_attn<<<2048, 256, 0, stream>>>(qb, kb, vtb, mask, po, dn);
  k_comb<<<2048, 256, 0, stream>>>(po, dn, ctx);
  k_gemm<2><<<256, 256, 0, stream>>>(ctx, woutT, bout, d_out, nullptr, 4096, 1024);
}